// Round 6
// baseline (100.596 us; speedup 1.0000x reference)
//
#include <hip/hip_runtime.h>

#define B_  4
#define C_  64
#define H_  256
#define W_  256
#define h_  64
#define w_  64
// s = 4, off = 2, r = 2, inv_2ss2 = 1/(2*2.5^2) = 0.08
// log2-domain spatial weights: -(d^2)*0.08*log2(e)
#define L2SW2 (-0.46166241f)
#define L2SW1 (-0.11541560f)

typedef float v2f __attribute__((ext_vector_type(2)));

// ---------------- per-batch partial sum / sumsq of guidance ------------------
// grid = 128 blocks (32 per batch); writes partials, NO atomics, no init needed.
__global__ void jbu_stats(const float* __restrict__ g, double* __restrict__ stats) {
    int b     = blockIdx.x >> 5;
    int slice = blockIdx.x & 31;
    const float4* p = (const float4*)(g + (size_t)b * 3 * H_ * W_) + (size_t)slice * 1536;
    double s = 0.0, s2 = 0.0;
    for (int i = threadIdx.x; i < 1536; i += 256) {
        float4 v = p[i];
        s  += (double)v.x + (double)v.y + (double)v.z + (double)v.w;
        s2 += (double)v.x * v.x + (double)v.y * v.y
            + (double)v.z * v.z + (double)v.w * v.w;
    }
    for (int off = 32; off > 0; off >>= 1) {
        s  += __shfl_down(s,  off);
        s2 += __shfl_down(s2, off);
    }
    __shared__ double ls[8];
    int wid  = threadIdx.x >> 6;
    int lane = threadIdx.x & 63;
    if (lane == 0) { ls[wid] = s; ls[4 + wid] = s2; }
    __syncthreads();
    if (threadIdx.x == 0) {
        stats[blockIdx.x]       = ls[0] + ls[1] + ls[2] + ls[3];
        stats[128 + blockIdx.x] = ls[4] + ls[5] + ls[6] + ls[7];
    }
}

// ---------------- fused main kernel (packed-f32 hot loop) --------------------
// grid = ((b*64 + y4)*4 + cg), 1024 blocks; block = 256 (lane = fine x)
// thread: 4 fine y (pairs {0,1},{2,3}) x fixed x x 16 channels (cg*16..)
__global__ __launch_bounds__(256, 4)
void jbu_mega16(const float* __restrict__ src, const float* __restrict__ guid,
                const double* __restrict__ stats, float* __restrict__ out) {
    // src tile: 5 rows x 64 cols x 16 ch, stride 20 floats (80 B, b128-aligned)
    __shared__ __align__(16) float sS[5 * 64 * 20];   // 25600 B
    // glow: (r,g,b, B-term) per coarse pixel, B = -invrl2*|gl|^2
    __shared__ __align__(16) float sG[5 * 64 * 4];    //  5120 B

    int cg  = blockIdx.x & 3;
    int y4  = (blockIdx.x >> 2) & 63;
    int b   = blockIdx.x >> 8;
    int tid = threadIdx.x;

    // ---- inv_2sr2 (log2 domain) from partials; uniform scalar loads overlap
    //      the staging below.
    double S = 0.0, S2 = 0.0;
    for (int i = 0; i < 32; ++i) {
        S  += stats[b * 32 + i];
        S2 += stats[128 + b * 32 + i];
    }
    const double n = 3.0 * H_ * W_;
    double var = (S2 - S * S / n) / (n - 1.0);
    float invrl2 = (float)(2.0 / var) * 1.44269504f;   // includes log2(e)

    int yi[5];
    #pragma unroll
    for (int d = 0; d < 5; ++d) {
        int u = y4 + d - 2;
        yi[d] = u < 0 ? 0 : (u > h_ - 1 ? h_ - 1 : u);
    }

    // ---- stage source tile: 4 coalesced dword loads + 1 ds_write_b128 / iter
    const float* sb = src + ((size_t)b * C_ + cg * 16) * h_ * w_;
    {
        int xx0 = tid & 63;
        int j4  = ((tid >> 6) & 3) * 4;
        #pragma unroll
        for (int it = 0; it < 5; ++it) {
            int yy = yi[it];
            float4 v;
            v.x = sb[((size_t)(j4 + 0) * h_ + yy) * w_ + xx0];
            v.y = sb[((size_t)(j4 + 1) * h_ + yy) * w_ + xx0];
            v.z = sb[((size_t)(j4 + 2) * h_ + yy) * w_ + xx0];
            v.w = sb[((size_t)(j4 + 3) * h_ + yy) * w_ + xx0];
            *(float4*)&sS[(it * 64 + xx0) * 20 + j4] = v;
        }
    }
    // ---- stage low-res guidance + B-term ----
    for (int k = tid; k < 320; k += 256) {
        int xx  = k & 63;
        int row = k >> 6;
        int u   = y4 + row - 2;
        int yy  = u < 0 ? 0 : (u > h_ - 1 ? h_ - 1 : u);
        const float* gbase = guid + (size_t)b * 3 * H_ * W_
                           + (size_t)(yy * 4 + 2) * W_ + (xx * 4 + 2);
        float gx = gbase[0];
        float gy = gbase[H_ * W_];
        float gz = gbase[2 * H_ * W_];
        float ss = fmaf(gz, gz, fmaf(gy, gy, gx * gx));
        float4 e = make_float4(gx, gy, gz, -invrl2 * ss);
        *(float4*)&sG[(row * 64 + xx) * 4] = e;
    }

    __syncthreads();

    int x  = tid;
    int y0 = y4 * 4;

    // high-res guidance, packed over pixel-pairs i={p0,p1},{p2,p3}:
    // gpx[i] holds 2*invrl2*gp for the pair; A2[i] = -invrl2*|gp|^2
    float gpr[4][3];
    #pragma unroll
    for (int c = 0; c < 3; ++c)
        #pragma unroll
        for (int p = 0; p < 4; ++p)
            gpr[p][c] = guid[(((size_t)b * 3 + c) * H_ + (y0 + p)) * W_ + x];
    float t2 = 2.0f * invrl2;
    v2f gpx[2], gpy[2], gpz[2], A2[2];
    #pragma unroll
    for (int i = 0; i < 2; ++i) {
        int p0 = 2 * i, p1 = 2 * i + 1;
        float s0 = fmaf(gpr[p0][2], gpr[p0][2],
                   fmaf(gpr[p0][1], gpr[p0][1], gpr[p0][0] * gpr[p0][0]));
        float s1 = fmaf(gpr[p1][2], gpr[p1][2],
                   fmaf(gpr[p1][1], gpr[p1][1], gpr[p1][0] * gpr[p1][0]));
        A2[i] = (v2f){-invrl2 * s0, -invrl2 * s1};
        gpx[i] = (v2f){t2 * gpr[p0][0], t2 * gpr[p1][0]};
        gpy[i] = (v2f){t2 * gpr[p0][1], t2 * gpr[p1][1]};
        gpz[i] = (v2f){t2 * gpr[p0][2], t2 * gpr[p1][2]};
    }

    int xb = x >> 2;
    int xi[5];
    #pragma unroll
    for (int d = 0; d < 5; ++d) {
        int v = xb + d - 2;
        xi[d] = v < 0 ? 0 : (v > w_ - 1 ? w_ - 1 : v);
    }

    const float l2sw[5] = {L2SW2, L2SW1, 0.0f, L2SW1, L2SW2};

    // acc2[p][q]: pixel p, channel-pair q (16 ch = 8 pairs)
    v2f acc2[4][8];
    v2f den2[2];
    #pragma unroll
    for (int p = 0; p < 4; ++p)
        #pragma unroll
        for (int q = 0; q < 8; ++q) acc2[p][q] = (v2f){0.f, 0.f};
    den2[0] = (v2f){0.f, 0.f};
    den2[1] = (v2f){0.f, 0.f};

    #pragma unroll
    for (int dy = 0; dy < 5; ++dy) {
        float l2y = l2sw[dy];
        int   rb  = dy * 64;
        #pragma unroll
        for (int dx = 0; dx < 5; ++dx) {
            int xx = xi[dx];
            float4 gl = *(const float4*)&sG[(rb + xx) * 4];
            float ct = gl.w + (l2y + l2sw[dx]);
            v2f glx = (v2f){gl.x, gl.x};
            v2f gly = (v2f){gl.y, gl.y};
            v2f glz = (v2f){gl.z, gl.z};
            v2f ct2 = (v2f){ct, ct};
            float wv[4];
            #pragma unroll
            for (int i = 0; i < 2; ++i) {
                v2f e = ct2 + A2[i];
                e = __builtin_elementwise_fma(gpx[i], glx, e);
                e = __builtin_elementwise_fma(gpy[i], gly, e);
                e = __builtin_elementwise_fma(gpz[i], glz, e);
                float w0 = __builtin_amdgcn_exp2f(e.x);
                float w1 = __builtin_amdgcn_exp2f(e.y);
                den2[i] += (v2f){w0, w1};
                wv[2 * i]     = w0;
                wv[2 * i + 1] = w1;
            }
            const float* sP = &sS[(rb + xx) * 20];
            #pragma unroll
            for (int h4 = 0; h4 < 4; ++h4) {
                float4 sv = *(const float4*)(sP + h4 * 4);
                v2f slo = (v2f){sv.x, sv.y};
                v2f shi = (v2f){sv.z, sv.w};
                #pragma unroll
                for (int p = 0; p < 4; ++p) {
                    v2f w2 = (v2f){wv[p], wv[p]};
                    acc2[p][h4 * 2 + 0] =
                        __builtin_elementwise_fma(w2, slo, acc2[p][h4 * 2 + 0]);
                    acc2[p][h4 * 2 + 1] =
                        __builtin_elementwise_fma(w2, shi, acc2[p][h4 * 2 + 1]);
                }
            }
        }
    }

    float* ob = out + ((size_t)b * C_ + cg * 16) * H_ * W_;
    float den[4] = {den2[0].x, den2[0].y, den2[1].x, den2[1].y};
    #pragma unroll
    for (int p = 0; p < 4; ++p) {
        float r = 1.0f / (den[p] + 1e-8f);
        int row = (y0 + p) * W_ + x;
        #pragma unroll
        for (int q = 0; q < 8; ++q) {
            ob[(size_t)(2 * q + 0) * H_ * W_ + row] = acc2[p][q].x * r;
            ob[(size_t)(2 * q + 1) * H_ * W_ + row] = acc2[p][q].y * r;
        }
    }
}

extern "C" void kernel_launch(void* const* d_in, const int* in_sizes, int n_in,
                              void* d_out, int out_size, void* d_ws, size_t ws_size,
                              hipStream_t stream) {
    const float* src  = (const float*)d_in[0];   // (4,64,64,64)
    const float* guid = (const float*)d_in[1];   // (4,3,256,256)
    float* out = (float*)d_out;                  // (4,64,256,256)

    double* stats = (double*)d_ws;               // 256 doubles: sum[128], sumsq[128]

    jbu_stats<<<128, 256, 0, stream>>>(guid, stats);
    jbu_mega16<<<B_ * 64 * 4, 256, 0, stream>>>(src, guid, stats, out);
}